// Round 1
// baseline (130.858 us; speedup 1.0000x reference)
//
#include <hip/hip_runtime.h>
#include <hip/hip_bf16.h>
#include <stdint.h>

// HausdorffLoss: N=M=4096, D=1024 fp32 inputs, scalar fp32 output.
// Strategy: bf16 MFMA GEMM for the cross term, fp32 norms, fused min epilogue.

#define NPTS 4096
#define MPTS 4096
#define DDIM 1024

typedef __attribute__((ext_vector_type(8))) short bf16x8;
typedef __attribute__((ext_vector_type(4))) float f32x4;

__device__ __forceinline__ unsigned short f2bf(float f) {
    unsigned int u = __float_as_uint(f);
    unsigned int r = 0x7FFFu + ((u >> 16) & 1u);   // round-to-nearest-even
    return (unsigned short)((u + r) >> 16);
}

__device__ __forceinline__ void gl_lds16(const void* g, void* l) {
    __builtin_amdgcn_global_load_lds(
        (const __attribute__((address_space(1))) unsigned int*)g,
        (__attribute__((address_space(3))) unsigned int*)l, 16, 0, 0);
}

// ---------------- prepass: fp32 -> bf16 + row squared norms ----------------
__global__ __launch_bounds__(256) void prepass_kernel(
    const float* __restrict__ s1, const float* __restrict__ s2,
    unsigned short* __restrict__ b1, unsigned short* __restrict__ b2,
    float* __restrict__ norms /* [8192]: x2 then y2 */) {
    int row = blockIdx.x;
    const float* src;
    unsigned short* dst;
    if (row < NPTS) { src = s1 + (size_t)row * DDIM; dst = b1 + (size_t)row * DDIM; }
    else            { src = s2 + (size_t)(row - NPTS) * DDIM; dst = b2 + (size_t)(row - NPTS) * DDIM; }
    int t = threadIdx.x;
    float4 v = ((const float4*)src)[t];          // 256 threads * 4 floats = 1024
    float sq = v.x * v.x + v.y * v.y + v.z * v.z + v.w * v.w;
    ushort4 o;
    o.x = f2bf(v.x); o.y = f2bf(v.y); o.z = f2bf(v.z); o.w = f2bf(v.w);
    ((ushort4*)dst)[t] = o;
    // block reduce sq
    #pragma unroll
    for (int off = 32; off; off >>= 1) sq += __shfl_down(sq, off, 64);
    __shared__ float red[4];
    if ((t & 63) == 0) red[t >> 6] = sq;
    __syncthreads();
    if (t == 0) norms[row] = red[0] + red[1] + red[2] + red[3];
}

// ---------------- fused GEMM + min epilogue ----------------
// 128x128 tile, BK=64, 4 waves (2x2, each 64x64), mfma_f32_16x16x32_bf16.
#define BM 128
#define BN 128
#define BK 64

__global__ __launch_bounds__(256) void cham_gemm_kernel(
    const unsigned short* __restrict__ A,   // set1 bf16 [4096][1024]
    const unsigned short* __restrict__ B,   // set2 bf16 [4096][1024]
    const float* __restrict__ x2, const float* __restrict__ y2,
    unsigned int* __restrict__ rowmin, unsigned int* __restrict__ colmin) {
    __shared__ unsigned short As[BM][BK];    // 16 KB, XOR-swizzled storage
    __shared__ unsigned short Bs[BN][BK];    // 16 KB

    const int bid = blockIdx.x;
    const int bi = bid >> 5;         // 32 col-blocks per row of blocks
    const int bj = bid & 31;
    const int tid = threadIdx.x;
    const int wave = tid >> 6;
    const int lane = tid & 63;
    const int wr = wave >> 1;        // wave row (0..1), 64 rows each
    const int wc = wave & 1;         // wave col (0..1), 64 cols each

    f32x4 acc[4][4];
    #pragma unroll
    for (int i = 0; i < 4; ++i)
        #pragma unroll
        for (int j = 0; j < 4; ++j)
            acc[i][j] = (f32x4){0.f, 0.f, 0.f, 0.f};

    const unsigned short* Ab = A + (size_t)(bi * BM) * DDIM;
    const unsigned short* Bb = B + (size_t)(bj * BN) * DDIM;
    const char* AsB = (const char*)&As[0][0];
    const char* BsB = (const char*)&Bs[0][0];

    const int lr = lane >> 3;        // 0..7   local row within 8-row issue
    const int ch = lane & 7;         // 0..7   16B chunk within 128B row

    for (int k0 = 0; k0 < DDIM; k0 += BK) {
        // ---- stage A and B tiles: linear LDS dest, inverse-swizzled global src
        #pragma unroll
        for (int q = 0; q < 4; ++q) {
            int r = wave * 32 + q * 8 + lr;                    // tile row 0..127
            int sch = ch ^ (r & 7);                            // swizzled source chunk
            gl_lds16(Ab + (size_t)r * DDIM + k0 + sch * 8, (void*)&As[wave * 32 + q * 8][0]);
            gl_lds16(Bb + (size_t)r * DDIM + k0 + sch * 8, (void*)&Bs[wave * 32 + q * 8][0]);
        }
        __syncthreads();             // drains vmcnt -> LDS tiles ready

        #pragma unroll
        for (int kk = 0; kk < 2; ++kk) {
            const int kb = kk * 32 + (lane >> 4) * 8;          // k base for this lane
            bf16x8 af[4], bfr[4];
            #pragma unroll
            for (int fi = 0; fi < 4; ++fi) {
                int row = wr * 64 + fi * 16 + (lane & 15);
                int off = row * (BK * 2) + kb * 2;
                af[fi] = *(const bf16x8*)(AsB + (off ^ ((row & 7) << 4)));
            }
            #pragma unroll
            for (int fj = 0; fj < 4; ++fj) {
                int col = wc * 64 + fj * 16 + (lane & 15);
                int off = col * (BK * 2) + kb * 2;
                bfr[fj] = *(const bf16x8*)(BsB + (off ^ ((col & 7) << 4)));
            }
            #pragma unroll
            for (int fi = 0; fi < 4; ++fi)
                #pragma unroll
                for (int fj = 0; fj < 4; ++fj)
                    acc[fi][fj] = __builtin_amdgcn_mfma_f32_16x16x32_bf16(
                        af[fi], bfr[fj], acc[fi][fj], 0, 0, 0);
        }
        __syncthreads();             // protect LDS overwrite next iter
    }

    // ---- epilogue: dist = (x2[n] + y2[m] - 2*xy) / D, fused row/col mins
    const float invD = 1.0f / (float)DDIM;
    const int nb = bi * BM + wr * 64;
    const int mb = bj * BN + wc * 64;

    float x2v[4][4];                 // [fi][reg]
    #pragma unroll
    for (int fi = 0; fi < 4; ++fi)
        #pragma unroll
        for (int rg = 0; rg < 4; ++rg)
            x2v[fi][rg] = x2[nb + fi * 16 + (lane >> 4) * 4 + rg];
    float y2v[4];                    // [fj]
    #pragma unroll
    for (int fj = 0; fj < 4; ++fj)
        y2v[fj] = y2[mb + fj * 16 + (lane & 15)];

    float rv[4][4];                  // per-row candidate mins [fi][reg]
    float cv[4];                     // per-col candidate mins [fj]
    #pragma unroll
    for (int fi = 0; fi < 4; ++fi)
        #pragma unroll
        for (int rg = 0; rg < 4; ++rg) rv[fi][rg] = 3.0e38f;
    #pragma unroll
    for (int fj = 0; fj < 4; ++fj) cv[fj] = 3.0e38f;

    #pragma unroll
    for (int fi = 0; fi < 4; ++fi)
        #pragma unroll
        for (int fj = 0; fj < 4; ++fj)
            #pragma unroll
            for (int rg = 0; rg < 4; ++rg) {
                float d = (x2v[fi][rg] + y2v[fj] - 2.0f * acc[fi][fj][rg]) * invD;
                rv[fi][rg] = fminf(rv[fi][rg], d);
                cv[fj] = fminf(cv[fj], d);
            }

    // row mins: reduce across the 16 lanes of each quad (cols), butterfly
    #pragma unroll
    for (int fi = 0; fi < 4; ++fi)
        #pragma unroll
        for (int rg = 0; rg < 4; ++rg) {
            float v = rv[fi][rg];
            v = fminf(v, __shfl_xor(v, 1, 64));
            v = fminf(v, __shfl_xor(v, 2, 64));
            v = fminf(v, __shfl_xor(v, 4, 64));
            v = fminf(v, __shfl_xor(v, 8, 64));
            if ((lane & 15) == 0) {
                int n = nb + fi * 16 + (lane >> 4) * 4 + rg;
                atomicMin(&rowmin[n], __float_as_uint(v));
            }
        }

    // col mins: reduce across quads (rows), butterfly over lane>>4
    #pragma unroll
    for (int fj = 0; fj < 4; ++fj) {
        float v = cv[fj];
        v = fminf(v, __shfl_xor(v, 16, 64));
        v = fminf(v, __shfl_xor(v, 32, 64));
        if (lane < 16) {
            int m = mb + fj * 16 + lane;
            atomicMin(&colmin[m], __float_as_uint(v));
        }
    }
}

// ---------------- final reduction ----------------
__global__ __launch_bounds__(1024) void finredux_kernel(
    const unsigned int* __restrict__ mins /* 8192 */, float* __restrict__ out) {
    int t = threadIdx.x;
    float s = 0.f;
    #pragma unroll
    for (int i = 0; i < 8; ++i) s += __uint_as_float(mins[t + i * 1024]);
    #pragma unroll
    for (int off = 32; off; off >>= 1) s += __shfl_down(s, off, 64);
    __shared__ float ws_[16];
    if ((t & 63) == 0) ws_[t >> 6] = s;
    __syncthreads();
    if (t == 0) {
        float tot = 0.f;
        #pragma unroll
        for (int i = 0; i < 16; ++i) tot += ws_[i];
        out[0] = tot * (1.0f / 8192.0f);   // (mean(rowmin)+mean(colmin))/2
    }
}

extern "C" void kernel_launch(void* const* d_in, const int* in_sizes, int n_in,
                              void* d_out, int out_size, void* d_ws, size_t ws_size,
                              hipStream_t stream) {
    const float* s1 = (const float*)d_in[0];
    const float* s2 = (const float*)d_in[1];
    char* ws = (char*)d_ws;

    unsigned short* b1 = (unsigned short*)ws;                         //  8 MB
    unsigned short* b2 = (unsigned short*)(ws + 8388608);             //  8 MB
    float* norms       = (float*)(ws + 16777216);                     // 32 KB (x2 ++ y2)
    unsigned int* mins = (unsigned int*)(ws + 16777216 + 32768);      // 32 KB (rowmin ++ colmin)
    float* out = (float*)d_out;

    // init mins to large positive float (0x7f7f7f7f ~ 3.39e38)
    hipMemsetAsync(mins, 0x7f, 32768, stream);

    prepass_kernel<<<NPTS + MPTS, 256, 0, stream>>>(s1, s2, b1, b2, norms);
    cham_gemm_kernel<<<(NPTS / BM) * (MPTS / BN), 256, 0, stream>>>(
        b1, b2, norms, norms + NPTS, mins, mins + NPTS);
    finredux_kernel<<<1, 1024, 0, stream>>>(mins, out);
}